// Round 10
// baseline (24.553 us; speedup 1.0000x reference)
//
#include <hip/hip_runtime.h>

typedef __attribute__((ext_vector_type(8))) short bf16x8;
typedef __attribute__((ext_vector_type(4))) float f32x4;

#define TT 256
#define SS 5
#define DD 32
#define ZP 68   // chunk-local row stride: %32==4 -> balanced b128 writes, 16B-aligned

#define MFMA(A, B, C) __builtin_amdgcn_mfma_f32_16x16x32_bf16((A), (B), (C), 0, 0, 0)

#define L2E 1.4426950408889634f

__device__ __forceinline__ float frcp(float v) { return __builtin_amdgcn_rcpf(v); }

// raw v_exp_f32: computes 2^x (no 1/ln2 premultiply)
__device__ __forceinline__ float exp2f_(float v) {
    float r;
    asm("v_exp_f32 %0, %1" : "=v"(r) : "v"(v));
    return r;
}

// packed fp32x2 -> bf16x2 (RNE), single HW instruction
__device__ __forceinline__ unsigned cvtpk(float lo, float hi) {
    unsigned r;
    asm("v_cvt_pk_bf16_f32 %0, %1, %2" : "=v"(r) : "v"(lo), "v"(hi));
    return r;
}

union F8 { unsigned u[4]; bf16x8 v; };

// split 8 fp32 into hi (RNE bf16) + lo (bf16 of residual): x ~= hi+lo, err ~2^-17|x|
__device__ __forceinline__ void split8(const float4 f0, const float4 f1, F8& h, F8& lo) {
    const float f[8] = {f0.x, f0.y, f0.z, f0.w, f1.x, f1.y, f1.z, f1.w};
    #pragma unroll
    for (int j = 0; j < 4; ++j) {
        const unsigned hp = cvtpk(f[2*j], f[2*j+1]);
        const float h0 = __uint_as_float(hp << 16);
        const float h1 = __uint_as_float(hp & 0xffff0000u);
        h.u[j] = hp;
        lo.u[j] = cvtpk(f[2*j] - h0, f[2*j+1] - h1);
    }
}

__device__ __forceinline__ float4 scal4(const float4 v, float s) {
    return make_float4(v.x * s, v.y * s, v.z * s, v.w * s);
}

// p *= dpp(p) with multiplicative identity fill (VALU-only scan step)
template<int CTRL, int RM>
__device__ __forceinline__ float dppmul(float p) {
    const int t = __builtin_amdgcn_update_dpp(
        __float_as_int(1.0f), __float_as_int(p), CTRL, RM, 0xf, false);
    return p * __int_as_float(t);
}

__device__ __forceinline__ float rdl63(float x) {
    return __int_as_float(__builtin_amdgcn_readlane(__float_as_int(x), 63));
}

__global__ void __launch_bounds__(256, 7)
mem_net_kernel(const float* __restrict__ x,
               const float* __restrict__ q,
               const float* __restrict__ keys,
               const float* __restrict__ Wu,
               const float* __restrict__ bu,
               const int*   __restrict__ lens,
               const int*   __restrict__ labels,
               const int*   __restrict__ qlab,
               float*       __restrict__ out)
{
    // per-WAVE private slices; all deps same-wave in-order, zero barriers
    __shared__ __align__(16) float zST[4][20][ZP];  // logits^T (log2e-scaled)
    __shared__ __align__(16) float cSS[4][ZP];      // per-row weight, chunk-local

    const int tid = threadIdx.x;
    const int l   = tid & 63;
    const int w   = tid >> 6;
    const int bb  = blockIdx.x * 4 + w;             // wave w owns batch bb
    const int n0  = l & 15;
    const int g   = l >> 4;
    const int kb  = g << 3;
    const int len = lens[bb];
    const int ql  = qlab[bb];

    // ---- r_attn = softmax_s(q . keys[ql][s]), in-register, all lanes ----
    float rS[SS];
    {
        const int d = l & 31;
        const float qv = q[(size_t)bb * DD + d] * L2E;   // log2e folded
        float pv[SS];
        #pragma unroll
        for (int s = 0; s < SS; ++s) pv[s] = qv * keys[(size_t)(ql * SS + s) * DD + d];
        #pragma unroll
        for (int m = 16; m >= 1; m >>= 1) {
            #pragma unroll
            for (int s = 0; s < SS; ++s) pv[s] += __shfl_xor(pv[s], m);
        }
        float mm = pv[0];
        #pragma unroll
        for (int s = 1; s < SS; ++s) mm = fmaxf(mm, pv[s]);
        float e[SS], sum = 0.f;
        #pragma unroll
        for (int s = 0; s < SS; ++s) { e[s] = exp2f_(pv[s] - mm); sum += e[s]; }
        const float inv = frcp(sum);
        #pragma unroll
        for (int s = 0; s < SS; ++s) rS[s] = e[s] * inv;
    }

    // ---- K_all^T B-fragments hi/lo, pre-scaled by log2e ----
    F8 kh0, kl0, kh1, kl1;
    {
        const float* kp = keys + (size_t)n0 * DD + kb;
        const float4 g0 = scal4(*reinterpret_cast<const float4*>(kp), L2E);
        const float4 g1 = scal4(*reinterpret_cast<const float4*>(kp + 4), L2E);
        split8(g0, g1, kh0, kl0);
        if (n0 < 4) {
            const float* kp1 = keys + (size_t)(16 + n0) * DD + kb;
            const float4 h0 = scal4(*reinterpret_cast<const float4*>(kp1), L2E);
            const float4 h1 = scal4(*reinterpret_cast<const float4*>(kp1 + 4), L2E);
            split8(h0, h1, kh1, kl1);
        } else {
            #pragma unroll
            for (int j = 0; j < 4; ++j) { kh1.u[j] = 0u; kl1.u[j] = 0u; }
        }
    }
    // ---- Wu B-fragments + bias, pre-scaled by log2e (sigmoid via exp2) ----
    F8 bw0, bw1;
    #pragma unroll
    for (int j = 0; j < 4; ++j) {
        const int k0 = kb + 2 * j;
        bw0.u[j] = cvtpk(Wu[k0 * DD + n0] * L2E,      Wu[(k0 + 1) * DD + n0] * L2E);
        bw1.u[j] = cvtpk(Wu[k0 * DD + n0 + 16] * L2E, Wu[(k0 + 1) * DD + n0 + 16] * L2E);
    }
    const float nb0 = -bu[n0] * L2E;        // negated scaled bias
    const float nb1 = -bu[n0 + 16] * L2E;

    // ---- chunks of 64 rows, high->low, carried suffix product ----
    float carry[SS] = {1.f, 1.f, 1.f, 1.f, 1.f};
    float p0 = 0.f, p1 = 0.f;

    for (int k = 3; k >= 0; --k) {
        const int c0 = k << 6;
        if (c0 >= len) continue;                     // wave-uniform skip

        const int rloc  = 63 - l;                    // reversed: prefix(lane)==suffix(row)
        const int rglob = c0 + rloc;
        const int labn  = labels[(size_t)bb * TT + rglob];

        // FRONT: QK^T via split-fp32 MFMA, transposed store (chunk-local rows)
        F8 xh[4];
        #pragma unroll
        for (int rt = 0; rt < 4; ++rt) {
            const int rbase = c0 + (rt << 4);
            if (rbase < len) {                       // wave-uniform
                const float* xt = x + ((size_t)bb * TT + rbase + n0) * DD + kb;
                const float4 f0 = *reinterpret_cast<const float4*>(xt);
                const float4 f1 = *reinterpret_cast<const float4*>(xt + 4);
                F8 xlo;
                split8(f0, f1, xh[rt], xlo);
                f32x4 z0 = {0.f, 0.f, 0.f, 0.f};
                f32x4 z1 = {0.f, 0.f, 0.f, 0.f};
                z0 = MFMA(xlo.v,    kh0.v, z0);
                z0 = MFMA(xh[rt].v, kl0.v, z0);
                z0 = MFMA(xh[rt].v, kh0.v, z0);
                z1 = MFMA(xlo.v,    kh1.v, z1);
                z1 = MFMA(xh[rt].v, kl1.v, z1);
                z1 = MFMA(xh[rt].v, kh1.v, z1);
                const int r0 = (rt << 4) + (g << 2); // C layout: col=n0, rows g*4+reg
                *reinterpret_cast<f32x4*>(&zST[w][n0][r0]) = z0;
                if (n0 < 4)
                    *reinterpret_cast<f32x4*>(&zST[w][16 + n0][r0]) = z1;
            }
        }
        asm volatile("s_waitcnt lgkmcnt(0)" ::: "memory");  // cross-lane zST read safety

        // softmax over the 5 label-selected (scaled) logits, exp2-based
        float a[SS];
        #pragma unroll
        for (int s = 0; s < SS; ++s) a[s] = 0.f;
        if (rglob < len) {
            const int lab = (rglob < len - 1) ? labn : 0;
            float z[SS];
            #pragma unroll
            for (int s = 0; s < SS; ++s) z[s] = zST[w][5 * lab + s][rloc];
            float m = z[0];
            #pragma unroll
            for (int s = 1; s < SS; ++s) m = fmaxf(m, z[s]);
            float e[SS], sum = 0.f;
            #pragma unroll
            for (int s = 0; s < SS; ++s) { e[s] = exp2f_(z[s] - m); sum += e[s]; }
            const float inv = frcp(sum);
            #pragma unroll
            for (int s = 0; s < SS; ++s) a[s] = e[s] * inv;
        }

        // exclusive prefix-product scan (DPP) + carry combine -> c
        float c = 0.f;
        #pragma unroll
        for (int s = 0; s < SS; ++s) {
            float ap = __shfl_up(a[s], 1);
            ap = (l == 0) ? 0.f : ap;
            float p = 1.f - ap;
            p = dppmul<0x111, 0xf>(p);               // row_shr:1
            p = dppmul<0x112, 0xf>(p);               // row_shr:2
            p = dppmul<0x114, 0xf>(p);               // row_shr:4
            p = dppmul<0x118, 0xf>(p);               // row_shr:8
            p = dppmul<0x142, 0xa>(p);               // row_bcast15 -> rows 1,3
            p = dppmul<0x143, 0xc>(p);               // row_bcast31 -> rows 2,3
            const float tot = rdl63(p) * (1.f - rdl63(a[s]));  // chunk total
            c += rS[s] * a[s] * p * carry[s];
            carry[s] *= tot;
        }
        cSS[w][rloc] = c;
        // cSS write->read same-wave: DS pipe in-order.

        // BACK: MLP MFMA + sigmoid(exp2) + c-weighted reduce.
        // Per-tile skip: a 16-row tile with all c <= 1e-6 contributes <= 1.6e-5.
        const unsigned long long bal = __ballot(c > 1e-6f);
        #pragma unroll
        for (int rt = 0; rt < 4; ++rt) {
            const unsigned long long tmask = 0xFFFFull << (48 - (rt << 4));
            if (bal & tmask) {                       // wave-uniform
                f32x4 acc0 = {0.f, 0.f, 0.f, 0.f};
                f32x4 acc1 = {0.f, 0.f, 0.f, 0.f};
                acc0 = MFMA(xh[rt].v, bw0.v, acc0);
                acc1 = MFMA(xh[rt].v, bw1.v, acc1);
                const float4 cf =
                    *reinterpret_cast<const float4*>(&cSS[w][(rt << 4) + (g << 2)]);
                const float cfa[4] = {cf.x, cf.y, cf.z, cf.w};
                #pragma unroll
                for (int rr = 0; rr < 4; ++rr) {
                    p0 += cfa[rr] * frcp(1.f + exp2f_(nb0 - acc0[rr]));
                    p1 += cfa[rr] * frcp(1.f + exp2f_(nb1 - acc1[rr]));
                }
            }
        }

        // EARLY EXIT: remaining (earlier) rows contribute <= sum_s rS[s]*carry[s]
        // <= max_s carry[s].  1e-4 is 200x under the 1.96e-2 threshold.
        // carry[] is lane-uniform (readlane-built), len wave-uniform -> uniform branch.
        float cmax = carry[0];
        #pragma unroll
        for (int s = 1; s < SS; ++s) cmax = fmaxf(cmax, carry[s]);
        if (cmax < 1e-4f) break;
    }

    // ---- in-wave reduce + direct store (no barrier, no LDS) ----
    p0 += __shfl_xor(p0, 16); p0 += __shfl_xor(p0, 32);
    p1 += __shfl_xor(p1, 16); p1 += __shfl_xor(p1, 32);
    if (l < 16) {
        out[(size_t)bb * DD + l]      = p0;
        out[(size_t)bb * DD + 16 + l] = p1;
    }
}

extern "C" void kernel_launch(void* const* d_in, const int* in_sizes, int n_in,
                              void* d_out, int out_size, void* d_ws, size_t ws_size,
                              hipStream_t stream) {
    const float* x      = (const float*)d_in[0];
    const float* q      = (const float*)d_in[1];
    const float* keys   = (const float*)d_in[2];
    const float* Wu     = (const float*)d_in[3];
    const float* bu     = (const float*)d_in[4];
    const int*   lens   = (const int*)d_in[5];
    const int*   labels = (const int*)d_in[6];
    const int*   qlab   = (const int*)d_in[7];
    float* out = (float*)d_out;

    hipLaunchKernelGGL(mem_net_kernel, dim3(4096 / 4), dim3(256), 0, stream,
                       x, q, keys, Wu, bu, lens, labels, qlab, out);
}

// Round 11
// 20.586 us; speedup vs baseline: 1.1927x; 1.1927x over previous
//
#include <hip/hip_runtime.h>

typedef __attribute__((ext_vector_type(8))) short bf16x8;
typedef __attribute__((ext_vector_type(4))) float f32x4;

#define TT 256
#define SS 5
#define DD 32
#define ZP 68   // chunk-local row stride: %32==4 -> balanced b128 writes, 16B-aligned

#define MFMA(A, B, C) __builtin_amdgcn_mfma_f32_16x16x32_bf16((A), (B), (C), 0, 0, 0)

#define L2E 1.4426950408889634f

__device__ __forceinline__ float frcp(float v) { return __builtin_amdgcn_rcpf(v); }

// raw v_exp_f32: computes 2^x (no 1/ln2 premultiply)
__device__ __forceinline__ float exp2f_(float v) {
    float r;
    asm("v_exp_f32 %0, %1" : "=v"(r) : "v"(v));
    return r;
}

// packed fp32x2 -> bf16x2 (RNE), single HW instruction
__device__ __forceinline__ unsigned cvtpk(float lo, float hi) {
    unsigned r;
    asm("v_cvt_pk_bf16_f32 %0, %1, %2" : "=v"(r) : "v"(lo), "v"(hi));
    return r;
}

union F8 { unsigned u[4]; bf16x8 v; };

// split 8 fp32 into hi (RNE bf16) + lo (bf16 of residual): x ~= hi+lo, err ~2^-17|x|
__device__ __forceinline__ void split8(const float4 f0, const float4 f1, F8& h, F8& lo) {
    const float f[8] = {f0.x, f0.y, f0.z, f0.w, f1.x, f1.y, f1.z, f1.w};
    #pragma unroll
    for (int j = 0; j < 4; ++j) {
        const unsigned hp = cvtpk(f[2*j], f[2*j+1]);
        const float h0 = __uint_as_float(hp << 16);
        const float h1 = __uint_as_float(hp & 0xffff0000u);
        h.u[j] = hp;
        lo.u[j] = cvtpk(f[2*j] - h0, f[2*j+1] - h1);
    }
}

__device__ __forceinline__ float4 scal4(const float4 v, float s) {
    return make_float4(v.x * s, v.y * s, v.z * s, v.w * s);
}

// p *= dpp(p) with multiplicative identity fill (VALU-only scan step)
template<int CTRL, int RM>
__device__ __forceinline__ float dppmul(float p) {
    const int t = __builtin_amdgcn_update_dpp(
        __float_as_int(1.0f), __float_as_int(p), CTRL, RM, 0xf, false);
    return p * __int_as_float(t);
}

__device__ __forceinline__ float rdl63(float x) {
    return __int_as_float(__builtin_amdgcn_readlane(__float_as_int(x), 63));
}

__global__ void __launch_bounds__(256, 6)
mem_net_kernel(const float* __restrict__ x,
               const float* __restrict__ q,
               const float* __restrict__ keys,
               const float* __restrict__ Wu,
               const float* __restrict__ bu,
               const int*   __restrict__ lens,
               const int*   __restrict__ labels,
               const int*   __restrict__ qlab,
               float*       __restrict__ out)
{
    // per-WAVE private slices; all deps same-wave in-order, zero barriers
    __shared__ __align__(16) float zST[4][20][ZP];  // logits^T (log2e-scaled)
    __shared__ __align__(16) float cSS[4][ZP];      // per-row weight, chunk-local

    const int tid = threadIdx.x;
    const int l   = tid & 63;
    const int w   = tid >> 6;
    const int bb  = blockIdx.x * 4 + w;             // wave w owns batch bb
    const int n0  = l & 15;
    const int g   = l >> 4;
    const int kb  = g << 3;
    const int len = lens[bb];
    const int ql  = qlab[bb];

    // ---- r_attn = softmax_s(q . keys[ql][s]), in-register, all lanes ----
    float rS[SS];
    {
        const int d = l & 31;
        const float qv = q[(size_t)bb * DD + d] * L2E;   // log2e folded
        float pv[SS];
        #pragma unroll
        for (int s = 0; s < SS; ++s) pv[s] = qv * keys[(size_t)(ql * SS + s) * DD + d];
        #pragma unroll
        for (int m = 16; m >= 1; m >>= 1) {
            #pragma unroll
            for (int s = 0; s < SS; ++s) pv[s] += __shfl_xor(pv[s], m);
        }
        float mm = pv[0];
        #pragma unroll
        for (int s = 1; s < SS; ++s) mm = fmaxf(mm, pv[s]);
        float e[SS], sum = 0.f;
        #pragma unroll
        for (int s = 0; s < SS; ++s) { e[s] = exp2f_(pv[s] - mm); sum += e[s]; }
        const float inv = frcp(sum);
        #pragma unroll
        for (int s = 0; s < SS; ++s) rS[s] = e[s] * inv;
    }

    // ---- K_all^T B-fragments hi/lo, pre-scaled by log2e ----
    F8 kh0, kl0, kh1, kl1;
    {
        const float* kp = keys + (size_t)n0 * DD + kb;
        const float4 g0 = scal4(*reinterpret_cast<const float4*>(kp), L2E);
        const float4 g1 = scal4(*reinterpret_cast<const float4*>(kp + 4), L2E);
        split8(g0, g1, kh0, kl0);
        if (n0 < 4) {
            const float* kp1 = keys + (size_t)(16 + n0) * DD + kb;
            const float4 h0 = scal4(*reinterpret_cast<const float4*>(kp1), L2E);
            const float4 h1 = scal4(*reinterpret_cast<const float4*>(kp1 + 4), L2E);
            split8(h0, h1, kh1, kl1);
        } else {
            #pragma unroll
            for (int j = 0; j < 4; ++j) { kh1.u[j] = 0u; kl1.u[j] = 0u; }
        }
    }
    // ---- Wu B-fragments + bias, pre-scaled by log2e (sigmoid via exp2) ----
    F8 bw0, bw1;
    #pragma unroll
    for (int j = 0; j < 4; ++j) {
        const int k0 = kb + 2 * j;
        bw0.u[j] = cvtpk(Wu[k0 * DD + n0] * L2E,      Wu[(k0 + 1) * DD + n0] * L2E);
        bw1.u[j] = cvtpk(Wu[k0 * DD + n0 + 16] * L2E, Wu[(k0 + 1) * DD + n0 + 16] * L2E);
    }
    const float nb0 = -bu[n0] * L2E;        // negated scaled bias
    const float nb1 = -bu[n0 + 16] * L2E;

    // ---- chunks of 64 rows, high->low, carried suffix product ----
    float carry[SS] = {1.f, 1.f, 1.f, 1.f, 1.f};
    float p0 = 0.f, p1 = 0.f;

    for (int k = 3; k >= 0; --k) {
        const int c0 = k << 6;
        if (c0 >= len) continue;                     // wave-uniform skip

        const int rloc  = 63 - l;                    // reversed: prefix(lane)==suffix(row)
        const int rglob = c0 + rloc;
        const int labn  = labels[(size_t)bb * TT + rglob];

        // FRONT: QK^T via split-fp32 MFMA, transposed store (chunk-local rows)
        F8 xh[4];
        #pragma unroll
        for (int rt = 0; rt < 4; ++rt) {
            const int rbase = c0 + (rt << 4);
            if (rbase < len) {                       // wave-uniform
                const float* xt = x + ((size_t)bb * TT + rbase + n0) * DD + kb;
                const float4 f0 = *reinterpret_cast<const float4*>(xt);
                const float4 f1 = *reinterpret_cast<const float4*>(xt + 4);
                F8 xlo;
                split8(f0, f1, xh[rt], xlo);
                f32x4 z0 = {0.f, 0.f, 0.f, 0.f};
                f32x4 z1 = {0.f, 0.f, 0.f, 0.f};
                z0 = MFMA(xlo.v,    kh0.v, z0);
                z0 = MFMA(xh[rt].v, kl0.v, z0);
                z0 = MFMA(xh[rt].v, kh0.v, z0);
                z1 = MFMA(xlo.v,    kh1.v, z1);
                z1 = MFMA(xh[rt].v, kl1.v, z1);
                z1 = MFMA(xh[rt].v, kh1.v, z1);
                const int r0 = (rt << 4) + (g << 2); // C layout: col=n0, rows g*4+reg
                *reinterpret_cast<f32x4*>(&zST[w][n0][r0]) = z0;
                if (n0 < 4)
                    *reinterpret_cast<f32x4*>(&zST[w][16 + n0][r0]) = z1;
            }
        }
        asm volatile("s_waitcnt lgkmcnt(0)" ::: "memory");  // cross-lane zST read safety

        // softmax over the 5 label-selected (scaled) logits, exp2-based
        float a[SS];
        #pragma unroll
        for (int s = 0; s < SS; ++s) a[s] = 0.f;
        if (rglob < len) {
            const int lab = (rglob < len - 1) ? labn : 0;
            float z[SS];
            #pragma unroll
            for (int s = 0; s < SS; ++s) z[s] = zST[w][5 * lab + s][rloc];
            float m = z[0];
            #pragma unroll
            for (int s = 1; s < SS; ++s) m = fmaxf(m, z[s]);
            float e[SS], sum = 0.f;
            #pragma unroll
            for (int s = 0; s < SS; ++s) { e[s] = exp2f_(z[s] - m); sum += e[s]; }
            const float inv = frcp(sum);
            #pragma unroll
            for (int s = 0; s < SS; ++s) a[s] = e[s] * inv;
        }

        // exclusive prefix-product scan (DPP) + carry combine -> c
        float c = 0.f;
        #pragma unroll
        for (int s = 0; s < SS; ++s) {
            float ap = __shfl_up(a[s], 1);
            ap = (l == 0) ? 0.f : ap;
            float p = 1.f - ap;
            p = dppmul<0x111, 0xf>(p);               // row_shr:1
            p = dppmul<0x112, 0xf>(p);               // row_shr:2
            p = dppmul<0x114, 0xf>(p);               // row_shr:4
            p = dppmul<0x118, 0xf>(p);               // row_shr:8
            p = dppmul<0x142, 0xa>(p);               // row_bcast15 -> rows 1,3
            p = dppmul<0x143, 0xc>(p);               // row_bcast31 -> rows 2,3
            const float tot = rdl63(p) * (1.f - rdl63(a[s]));  // chunk total
            c += rS[s] * a[s] * p * carry[s];
            carry[s] *= tot;
        }
        cSS[w][rloc] = c;
        // cSS write->read same-wave: DS pipe in-order.

        // BACK: MLP MFMA + sigmoid(exp2) + c-weighted reduce.
        // Per-tile skip: a 16-row tile with all c <= 1e-6 contributes <= 1.6e-5.
        const unsigned long long bal = __ballot(c > 1e-6f);
        #pragma unroll
        for (int rt = 0; rt < 4; ++rt) {
            const unsigned long long tmask = 0xFFFFull << (48 - (rt << 4));
            if (bal & tmask) {                       // wave-uniform
                f32x4 acc0 = {0.f, 0.f, 0.f, 0.f};
                f32x4 acc1 = {0.f, 0.f, 0.f, 0.f};
                acc0 = MFMA(xh[rt].v, bw0.v, acc0);
                acc1 = MFMA(xh[rt].v, bw1.v, acc1);
                const float4 cf =
                    *reinterpret_cast<const float4*>(&cSS[w][(rt << 4) + (g << 2)]);
                const float cfa[4] = {cf.x, cf.y, cf.z, cf.w};
                #pragma unroll
                for (int rr = 0; rr < 4; ++rr) {
                    p0 += cfa[rr] * frcp(1.f + exp2f_(nb0 - acc0[rr]));
                    p1 += cfa[rr] * frcp(1.f + exp2f_(nb1 - acc1[rr]));
                }
            }
        }

        // EARLY EXIT: remaining (earlier) rows contribute <= sum_s rS[s]*carry[s]
        // <= max_s carry[s].  1e-4 is 200x under the 1.96e-2 threshold.
        // carry[] is lane-uniform (readlane-built), len wave-uniform -> uniform branch.
        float cmax = carry[0];
        #pragma unroll
        for (int s = 1; s < SS; ++s) cmax = fmaxf(cmax, carry[s]);
        if (cmax < 1e-4f) break;
    }

    // ---- in-wave reduce + direct store (no barrier, no LDS) ----
    p0 += __shfl_xor(p0, 16); p0 += __shfl_xor(p0, 32);
    p1 += __shfl_xor(p1, 16); p1 += __shfl_xor(p1, 32);
    if (l < 16) {
        out[(size_t)bb * DD + l]      = p0;
        out[(size_t)bb * DD + 16 + l] = p1;
    }
}

extern "C" void kernel_launch(void* const* d_in, const int* in_sizes, int n_in,
                              void* d_out, int out_size, void* d_ws, size_t ws_size,
                              hipStream_t stream) {
    const float* x      = (const float*)d_in[0];
    const float* q      = (const float*)d_in[1];
    const float* keys   = (const float*)d_in[2];
    const float* Wu     = (const float*)d_in[3];
    const float* bu     = (const float*)d_in[4];
    const int*   lens   = (const int*)d_in[5];
    const int*   labels = (const int*)d_in[6];
    const int*   qlab   = (const int*)d_in[7];
    float* out = (float*)d_out;

    hipLaunchKernelGGL(mem_net_kernel, dim3(4096 / 4), dim3(256), 0, stream,
                       x, q, keys, Wu, bu, lens, labels, qlab, out);
}